// Round 1
// 1402.190 us; speedup vs baseline: 1.1986x; 1.1986x over previous
//
#include <hip/hip_runtime.h>

#define HWN 16384
#define WDIM 128

typedef __bf16 bf16x8 __attribute__((ext_vector_type(8)));
typedef float floatx4 __attribute__((ext_vector_type(4)));

#define LSTR 44  // LDS row stride in bf16 (pad 32->44: staging writes & frag reads <=2-way)

// ---------- MFMA GEMM: C[M,16384] = (Ah+Al)[M,K] x split(B)[K,16384], fp32-quality ----------
// 128x128 tile, BK=32, 4 waves (2x2 quadrants of 64x64), 16x16x32 bf16 MFMA, 3 products.
__global__ __launch_bounds__(256, 2) void gemm_mfma3(
    const __bf16* __restrict__ Ah, const __bf16* __restrict__ Al,
    const float* __restrict__ B, float* __restrict__ C,
    int K, long sA, long sB, long sC) {
  __shared__ __bf16 sAh[128 * LSTR], sAl[128 * LSTR], sBh[128 * LSTR], sBl[128 * LSTR];
  const int bz = blockIdx.z;
  Ah += (long)bz * sA;
  Al += (long)bz * sA;
  B += (long)bz * sB;
  C += (long)bz * sC;
  const int tid = threadIdx.x;
  const int n0 = blockIdx.x << 7, m0 = blockIdx.y << 7;
  // staging assignments
  const int arow = tid >> 1, akq = (tid & 1) << 4;  // A: 2 threads/row, 16 k each
  const int bn = (tid & 63) << 1;                   // B: pixel pair
  const int bkb = (tid >> 6) << 3;                  // B: k-block of 8 (per wave)
  // fragment assignments
  const int lane = tid & 63, wv = tid >> 6;
  const int mq = (wv & 1) << 6, nq = (wv >> 1) << 6;
  const int fm = lane & 15, fq = lane >> 4;
  floatx4 acc[4][4] = {};
  for (int k0 = 0; k0 < K; k0 += 32) {
    // global loads (before barrier)
    const __bf16* pAh = Ah + (long)(m0 + arow) * K + k0 + akq;
    const __bf16* pAl = Al + (long)(m0 + arow) * K + k0 + akq;
    bf16x8 a0 = *(const bf16x8*)pAh;
    bf16x8 a1 = *(const bf16x8*)(pAh + 8);
    bf16x8 a2 = *(const bf16x8*)pAl;
    bf16x8 a3 = *(const bf16x8*)(pAl + 8);
    const float* pB = B + (long)(k0 + bkb) * HWN + n0 + bn;
    float2 v[8];
#pragma unroll
    for (int r = 0; r < 8; ++r) v[r] = *(const float2*)(pB + (long)r * HWN);
    bf16x8 bh0, bh1, bl0, bl1;
#pragma unroll
    for (int r = 0; r < 8; ++r) {
      float vx = v[r].x, vy = v[r].y;
      __bf16 hx = (__bf16)vx, hy = (__bf16)vy;
      bh0[r] = hx;
      bh1[r] = hy;
      bl0[r] = (__bf16)(vx - (float)hx);
      bl1[r] = (__bf16)(vy - (float)hy);
    }
    __syncthreads();  // previous iter's frag reads done
    *(bf16x8*)&sAh[arow * LSTR + akq] = a0;
    *(bf16x8*)&sAh[arow * LSTR + akq + 8] = a1;
    *(bf16x8*)&sAl[arow * LSTR + akq] = a2;
    *(bf16x8*)&sAl[arow * LSTR + akq + 8] = a3;
    *(bf16x8*)&sBh[bn * LSTR + bkb] = bh0;
    *(bf16x8*)&sBh[(bn + 1) * LSTR + bkb] = bh1;
    *(bf16x8*)&sBl[bn * LSTR + bkb] = bl0;
    *(bf16x8*)&sBl[(bn + 1) * LSTR + bkb] = bl1;
    __syncthreads();
    bf16x8 fAh[4], fAl[4];
#pragma unroll
    for (int i = 0; i < 4; ++i) {
      fAh[i] = *(const bf16x8*)&sAh[(mq + i * 16 + fm) * LSTR + fq * 8];
      fAl[i] = *(const bf16x8*)&sAl[(mq + i * 16 + fm) * LSTR + fq * 8];
    }
#pragma unroll
    for (int j = 0; j < 4; ++j) {
      bf16x8 bh = *(const bf16x8*)&sBh[(nq + j * 16 + fm) * LSTR + fq * 8];
      bf16x8 bl = *(const bf16x8*)&sBl[(nq + j * 16 + fm) * LSTR + fq * 8];
#pragma unroll
      for (int i = 0; i < 4; ++i) {
        acc[i][j] = __builtin_amdgcn_mfma_f32_16x16x32_bf16(fAh[i], bh, acc[i][j], 0, 0, 0);
        acc[i][j] = __builtin_amdgcn_mfma_f32_16x16x32_bf16(fAl[i], bh, acc[i][j], 0, 0, 0);
        acc[i][j] = __builtin_amdgcn_mfma_f32_16x16x32_bf16(fAh[i], bl, acc[i][j], 0, 0, 0);
      }
    }
  }
#pragma unroll
  for (int i = 0; i < 4; ++i)
#pragma unroll
    for (int j = 0; j < 4; ++j) {
      const int col = n0 + nq + j * 16 + fm;
#pragma unroll
      for (int r = 0; r < 4; ++r) {
        const int row = m0 + mq + i * 16 + fq * 4 + r;
        C[(long)row * HWN + col] = acc[i][j][r];
      }
    }
}

// ---------- split fp32 -> bf16 hi/lo ----------
__global__ __launch_bounds__(256) void split_w(
    const float* __restrict__ w, __bf16* __restrict__ hi, __bf16* __restrict__ lo, int n) {
  int i = blockIdx.x * 256 + threadIdx.x;
  if (i < n) {
    float v = w[i];
    __bf16 h = (__bf16)v;
    hi[i] = h;
    lo[i] = (__bf16)(v - (float)h);
  }
}

// ---------- dw_all2: depthwise 3x3, LDS-free, float4 in/out, shfl halo ----------
// One block per (channel, batch). 256 threads: thread = (xg, rg),
// xg in [0,32): cols xg*4..xg*4+3; rg in [0,8): rows rg*16..rg*16+15.
// Left/right neighbors via __shfl of the adjacent lane's float4 edge elements.
__global__ __launch_bounds__(256) void dw_all2(
    const float* __restrict__ qkv1, const float* __restrict__ dww,
    float* __restrict__ dwout, float* __restrict__ qs, float* __restrict__ ks, int b0) {
  const int tid = threadIdx.x;
  const int ch = blockIdx.x;
  const int bz = blockIdx.y;
  const int xg = tid & 31;
  const int rg = tid >> 5;
  const float4* P = (const float4*)(qkv1 + ((long)bz * 1152 + ch) * HWN);
  float4* O = (float4*)(dwout + ((long)bz * 1152 + ch) * HWN);
  const float* wp = dww + (long)ch * 9;
  const float w00 = wp[0], w01 = wp[1], w02 = wp[2];
  const float w10 = wp[3], w11 = wp[4], w12 = wp[5];
  const float w20 = wp[6], w21 = wp[7], w22 = wp[8];
  const int y0 = rg << 4;

  float e[3][6];
#define LOADROW(Y, E)                                   \
  {                                                     \
    float4 v = make_float4(0.f, 0.f, 0.f, 0.f);         \
    int yy = (Y);                                       \
    if (yy >= 0 && yy < WDIM) v = P[yy * 32 + xg];      \
    float lft = __shfl_up(v.w, 1, 64);                  \
    float rgt = __shfl_down(v.x, 1, 64);                \
    (E)[0] = (xg == 0) ? 0.f : lft;                     \
    (E)[1] = v.x;                                       \
    (E)[2] = v.y;                                       \
    (E)[3] = v.z;                                       \
    (E)[4] = v.w;                                       \
    (E)[5] = (xg == 31) ? 0.f : rgt;                    \
  }

  LOADROW(y0 - 1, e[0]);
  LOADROW(y0, e[1]);
  float sq = 0.f;
#pragma unroll
  for (int i = 0; i < 16; ++i) {
    LOADROW(y0 + i + 1, e[(i + 2) % 3]);
    const float* t = e[i % 3];
    const float* m = e[(i + 1) % 3];
    const float* btm = e[(i + 2) % 3];
    float oarr[4];
#pragma unroll
    for (int j = 0; j < 4; ++j) {
      oarr[j] = w00 * t[j] + w01 * t[j + 1] + w02 * t[j + 2]
              + w10 * m[j] + w11 * m[j + 1] + w12 * m[j + 2]
              + w20 * btm[j] + w21 * btm[j + 1] + w22 * btm[j + 2];
      sq += oarr[j] * oarr[j];
    }
    O[(y0 + i) * 32 + xg] = make_float4(oarr[0], oarr[1], oarr[2], oarr[3]);
  }
#undef LOADROW

  if (ch < 768) {
#pragma unroll
    for (int off = 32; off >= 1; off >>= 1) sq += __shfl_down(sq, off, 64);
    if ((tid & 63) == 0) {
      int b = b0 + bz;
      if (ch < 384)
        atomicAdd(qs + b * 384 + ch, sq);
      else
        atomicAdd(ks + b * 384 + (ch - 384), sq);
    }
  }
}

// ---------- gram256: G[b,h] += Qd(48,P) * Kd(48,P)^T, 256 threads, float4 staged ----------
#define GPAD 132
__global__ __launch_bounds__(256) void gram256(
    const float* __restrict__ dwout, float* __restrict__ gram, int b0) {
  __shared__ float qt[48 * GPAD];
  __shared__ float kt[48 * GPAD];
  const int tid = threadIdx.x;
  const int kc = blockIdx.x;  // 32 chunks of 512 px
  const int h = blockIdx.y;
  const int bz = blockIdx.z;
  const float* Q = dwout + ((long)bz * 1152 + h * 48) * HWN;
  const float* K = Q + 384L * HWN;
  const int c0 = (tid & 15) * 3;
  const int d0 = (tid >> 4) * 3;
  float g[3][3] = {};
  for (int p0 = kc * 512; p0 < kc * 512 + 512; p0 += 128) {
    __syncthreads();  // previous stage's LDS reads done
#pragma unroll
    for (int i = tid; i < 1536; i += 256) {
      int r = i >> 5, x4 = (i & 31) << 2;
      *(float4*)&qt[r * GPAD + x4] = *(const float4*)(Q + (long)r * HWN + p0 + x4);
      *(float4*)&kt[r * GPAD + x4] = *(const float4*)(K + (long)r * HWN + p0 + x4);
    }
    __syncthreads();
#pragma unroll 4
    for (int p = 0; p < 128; p += 4) {
      float4 qv[3], kv[3];
#pragma unroll
      for (int i = 0; i < 3; ++i) qv[i] = *(const float4*)&qt[(c0 + i) * GPAD + p];
#pragma unroll
      for (int j = 0; j < 3; ++j) kv[j] = *(const float4*)&kt[(d0 + j) * GPAD + p];
#pragma unroll
      for (int i = 0; i < 3; ++i)
#pragma unroll
        for (int j = 0; j < 3; ++j)
          g[i][j] += qv[i].x * kv[j].x + qv[i].y * kv[j].y + qv[i].z * kv[j].z +
                     qv[i].w * kv[j].w;
    }
  }
  float* gb = gram + (long)((b0 + bz) * 8 + h) * 2304;
#pragma unroll
  for (int i = 0; i < 3; ++i)
#pragma unroll
    for (int j = 0; j < 3; ++j) atomicAdd(gb + (c0 + i) * 48 + (d0 + j), g[i][j]);
}

// ---------- K3: normalize Gram, top-7, masked softmax -> attn ----------
__global__ __launch_bounds__(64) void topk_softmax(
    const float* __restrict__ gram, const float* __restrict__ qs, const float* __restrict__ ks,
    const float* __restrict__ temp, float* __restrict__ attn, int b0) {
  const int z = blockIdx.x;
  const int b = b0 + (z >> 3), h = z & 7;
  __shared__ float kn[48];
  const int tid = threadIdx.x;
  if (tid < 48) kn[tid] = fmaxf(sqrtf(ks[b * 384 + h * 48 + tid]), 1e-12f);
  __syncthreads();
  if (tid >= 48) return;
  const int c = tid;
  float qn = fmaxf(sqrtf(qs[b * 384 + h * 48 + c]), 1e-12f);
  float tv = temp[h];
  const float* gr = gram + (long)(b * 8 + h) * 2304 + c * 48;
  float s[48];
#pragma unroll
  for (int d = 0; d < 48; ++d) s[d] = gr[d] / (qn * kn[d]) * tv;
  unsigned long long sel = 0ull;
  float m0 = 0.f;
  for (int it = 0; it < 7; ++it) {
    float mx = -3.0e38f;
    int mi = 0;
#pragma unroll
    for (int d = 0; d < 48; ++d) {
      bool taken = (sel >> d) & 1ull;
      if (!taken && s[d] > mx) { mx = s[d]; mi = d; }
    }
    sel |= (1ull << mi);
    if (it == 0) m0 = mx;
  }
  float sum = 0.f;
  float e[48];
#pragma unroll
  for (int d = 0; d < 48; ++d) {
    bool t = (sel >> d) & 1ull;
    float ev = t ? expf(s[d] - m0) : 0.f;
    e[d] = ev;
    sum += ev;
  }
  float inv = 1.f / sum;
  float* ar = attn + (long)(b * 8 + h) * 2304 + c * 48;
#pragma unroll
  for (int d = 0; d < 48; ++d) ar[d] = e[d] * inv;
}

// ---------- K4: M_b = proj_w @ blockdiag(attn_b) -> split bf16 hi/lo ----------
__global__ __launch_bounds__(256) void build_M(
    const float* __restrict__ attn, const float* __restrict__ pw,
    __bf16* __restrict__ Mh, __bf16* __restrict__ Ml, int b0) {
  const int b = b0 + blockIdx.x;
  const int h = blockIdx.y;
  __shared__ float at[48][49];
  const int tid = threadIdx.x;
  for (int i = tid; i < 2304; i += 256) at[i / 48][i % 48] = attn[(long)(b * 8 + h) * 2304 + i];
  __syncthreads();
  for (int idx = tid; idx < 384 * 48; idx += 256) {
    int o = idx / 48, d = idx % 48;
    const float* pr = pw + (long)o * 384 + h * 48;
    float acc = 0.f;
#pragma unroll
    for (int c = 0; c < 48; ++c) acc += pr[c] * at[c][d];
    long oi = ((long)b * 384 + o) * 384 + h * 48 + d;
    __bf16 hh = (__bf16)acc;
    Mh[oi] = hh;
    Ml[oi] = (__bf16)(acc - (float)hh);
  }
}

extern "C" void kernel_launch(void* const* d_in, const int* in_sizes, int n_in,
                              void* d_out, int out_size, void* d_ws, size_t ws_size,
                              hipStream_t stream) {
  const float* x = (const float*)d_in[0];       // (8,384,128,128)
  const float* qkv_w = (const float*)d_in[1];   // (1152,384)
  const float* dw_w = (const float*)d_in[2];    // (1152,1,3,3)
  const float* proj_w = (const float*)d_in[3];  // (384,384)
  const float* temp = (const float*)d_in[4];    // (8,)
  float* out = (float*)d_out;
  float* ws = (float*)d_ws;

  // ws layout
  float* gram = ws;                          // 147456 f
  float* qs = gram + 147456;                 // 3072 f
  float* ks = qs + 3072;                     // 3072 f
  float* attn = ks + 3072;                   // 147456 f
  __bf16* Wh = (__bf16*)(attn + 147456);     // 442368 bf16
  __bf16* Wl = Wh + 442368;                  // 442368 bf16
  __bf16* Mh = Wl + 442368;                  // 8*147456 bf16
  __bf16* Ml = Mh + 1179648;                 // 8*147456 bf16
  float* qkv1 = (float*)(Ml + 1179648);      // nb*1152*16384 f
  const long SMALLS = 1333248L;              // floats
  const long PERB = 37748736L;               // qkv1 + dwout per batch (floats)
  long wsf = (long)(ws_size / 4);
  int nb = (int)((wsf - SMALLS) / PERB);
  if (nb < 1) nb = 1;
  if (nb > 8) nb = 8;
  float* dwout = qkv1 + (long)nb * 18874368L;

  hipMemsetAsync(gram, 0, (147456 + 3072 + 3072) * sizeof(float), stream);
  split_w<<<dim3((442368 + 255) / 256), 256, 0, stream>>>(qkv_w, Wh, Wl, 442368);

  for (int b0 = 0; b0 < 8; b0 += nb) {
    int nbc = (8 - b0 < nb) ? (8 - b0) : nb;
    // K1: qkv1 = W @ x[b]   (M=1152, K=384), split-bf16 MFMA
    gemm_mfma3<<<dim3(128, 9, nbc), 256, 0, stream>>>(
        Wh, Wl, x + (long)b0 * 6291456L, qkv1, 384, 0L, 6291456L, 18874368L);
    // dw: all 1152 channels, q/k sumsq fused (LDS-free float4 version)
    dw_all2<<<dim3(1152, nbc), 256, 0, stream>>>(qkv1, dw_w, dwout, qs, ks, b0);
    // gram
    gram256<<<dim3(32, 8, nbc), 256, 0, stream>>>(dwout, gram, b0);
    // attn
    topk_softmax<<<dim3(nbc * 8), 64, 0, stream>>>(gram, qs, ks, temp, attn, b0);
    // M_b (split bf16)
    build_M<<<dim3(nbc, 8), 256, 0, stream>>>(attn, proj_w, Mh, Ml, b0);
    // K5: out[b] = M_b @ v[b]   (M=384, K=384), split-bf16 MFMA
    gemm_mfma3<<<dim3(128, 3, nbc), 256, 0, stream>>>(
        Mh + (long)b0 * 147456L, Ml + (long)b0 * 147456L, dwout + 768L * HWN,
        out + (long)b0 * 6291456L, 384, 147456L, 18874368L, 6291456L);
  }
}